// Round 1
// baseline (390.941 us; speedup 1.0000x reference)
//
#include <hip/hip_runtime.h>
#include <hip/hip_bf16.h>

// Problem constants: B=2, S=2048, H=16, dk=64, D_MODEL=1024, THETA=10000
#define NB 2
#define NS 2048
#define NH 16
#define NDK 64
#define NDM 1024

using u16 = unsigned short;
typedef __attribute__((ext_vector_type(8))) short short8;
typedef __attribute__((ext_vector_type(4))) float f32x4;

__device__ __forceinline__ float bf2f(u16 v) {
  unsigned u = ((unsigned)v) << 16; float f; __builtin_memcpy(&f, &u, 4); return f;
}
__device__ __forceinline__ u16 f2bf(float f) {
  unsigned u; __builtin_memcpy(&u, &f, 4);
  return (u16)((u + 0x7fffu + ((u >> 16) & 1u)) >> 16);
}

__device__ __forceinline__ void gload_lds16(const void* g, void* l) {
  __builtin_amdgcn_global_load_lds((const __attribute__((address_space(1))) unsigned*)g,
                                   (__attribute__((address_space(3))) unsigned*)l, 16, 0, 0);
}

// ---------------- fp32 -> bf16 convert (vectorized) ----------------
__global__ __launch_bounds__(256) void cvt_f32_bf16(const float* __restrict__ in,
                                                    u16* __restrict__ out, int n4) {
  int i = blockIdx.x * 256 + threadIdx.x;
  if (i < n4) {
    float4 v = *(const float4*)(in + (size_t)i * 4);
    unsigned lo = f2bf(v.x) | ((unsigned)f2bf(v.y) << 16);
    unsigned hi = f2bf(v.z) | ((unsigned)f2bf(v.w) << 16);
    uint2 w; w.x = lo; w.y = hi;
    *(uint2*)(out + (size_t)i * 4) = w;
  }
}

// ---------------- GEMM: C[M,N] = A[M,K] * B[N,K]^T, bf16 in, fp32 acc ----------------
// 128x128 tile, BK=32, 4 waves (2x2 of 64x64), global_load_lds 16B staging.
template <typename OutT>
__global__ __launch_bounds__(256) void gemm_bt(const u16* __restrict__ A, const u16* __restrict__ B,
                                               OutT* __restrict__ C, int M, int N, int K) {
  __shared__ u16 As[128 * 32];
  __shared__ u16 Bs[128 * 32];
  const int tid = threadIdx.x;
  const int wave = tid >> 6;
  const int lane = tid & 63;
  const int m0 = blockIdx.x * 128;
  const int n0 = blockIdx.y * 128;
  const int wm = (wave >> 1) * 64;
  const int wn = (wave & 1) * 64;

  f32x4 acc[4][4];
#pragma unroll
  for (int m = 0; m < 4; ++m)
#pragma unroll
    for (int n = 0; n < 4; ++n) acc[m][n] = (f32x4){0.f, 0.f, 0.f, 0.f};

  // staging: each wave-issue moves 64 lanes * 16B = 1KB = 16 rows of 32 bf16
  const int srow = lane >> 2;       // 0..15
  const int scol = (lane & 3) * 8;  // k element offset
  const u16* Ag0 = A + (size_t)(m0 + wave * 16 + srow) * K + scol;
  const u16* Ag1 = A + (size_t)(m0 + 64 + wave * 16 + srow) * K + scol;
  const u16* Bg0 = B + (size_t)(n0 + wave * 16 + srow) * K + scol;
  const u16* Bg1 = B + (size_t)(n0 + 64 + wave * 16 + srow) * K + scol;
  u16* AsW0 = As + (wave * 16) * 32;
  u16* AsW1 = As + (64 + wave * 16) * 32;
  u16* BsW0 = Bs + (wave * 16) * 32;
  u16* BsW1 = Bs + (64 + wave * 16) * 32;

  const int fr = lane & 15;
  const int fk = (lane >> 4) * 8;

  for (int k0 = 0; k0 < K; k0 += 32) {
    __syncthreads();
    gload_lds16(Ag0 + k0, AsW0);
    gload_lds16(Ag1 + k0, AsW1);
    gload_lds16(Bg0 + k0, BsW0);
    gload_lds16(Bg1 + k0, BsW1);
    __syncthreads();

    short8 af[4], bf[4];
#pragma unroll
    for (int m = 0; m < 4; ++m)
      af[m] = *(const short8*)(As + (wm + m * 16 + fr) * 32 + fk);
#pragma unroll
    for (int n = 0; n < 4; ++n)
      bf[n] = *(const short8*)(Bs + (wn + n * 16 + fr) * 32 + fk);
#pragma unroll
    for (int m = 0; m < 4; ++m)
#pragma unroll
      for (int n = 0; n < 4; ++n)
        acc[m][n] = __builtin_amdgcn_mfma_f32_16x16x32_bf16(af[m], bf[n], acc[m][n], 0, 0, 0);
  }

  const int fg = lane >> 4;
#pragma unroll
  for (int m = 0; m < 4; ++m)
#pragma unroll
    for (int n = 0; n < 4; ++n)
#pragma unroll
      for (int r = 0; r < 4; ++r) {
        int row = m0 + wm + m * 16 + fg * 4 + r;
        int col = n0 + wn + n * 16 + fr;
        if constexpr (sizeof(OutT) == 2)
          C[(size_t)row * N + col] = (OutT)f2bf(acc[m][n][r]);
        else
          C[(size_t)row * N + col] = (OutT)acc[m][n][r];
      }
}

// ---------------- RoPE on Q,K: qkv[B,S,3072] -> Qr,Kr [B,H,S,64] ----------------
__global__ __launch_bounds__(256) void rope_qk(const u16* __restrict__ qkv, const int* __restrict__ pos,
                                               u16* __restrict__ Qr, u16* __restrict__ Kr) {
  int t = blockIdx.x * 256 + threadIdx.x;  // B*S*H*32 = 2^21
  int i = t & 31;
  int h = (t >> 5) & 15;
  int s = (t >> 9) & 2047;
  int b = t >> 20;
  float p = (float)pos[(b << 11) + s];
  // freq = 10000^(-2i/64) = exp2(-i * (2/64)*log2(10000))
  float ang = p * __builtin_exp2f(-(float)i * 0.41524101186f);
  float sn, cs;
  sincosf(ang, &sn, &cs);
  const u16* base = qkv + ((size_t)((b << 11) + s)) * 3072 + h * 64 + 2 * i;
  float qe = bf2f(base[0]), qo = bf2f(base[1]);
  float ke = bf2f(base[1024]), ko = bf2f(base[1025]);
  size_t o = (((size_t)((b << 4) + h) << 11) + s) * 64 + 2 * i;
  unsigned qw = f2bf(cs * qe - sn * qo) | ((unsigned)f2bf(sn * qe + cs * qo) << 16);
  unsigned kw = f2bf(cs * ke - sn * ko) | ((unsigned)f2bf(sn * ke + cs * ko) << 16);
  *(unsigned*)(Qr + o) = qw;
  *(unsigned*)(Kr + o) = kw;
}

// ---------------- V transpose: qkv V-part -> Vt [B,H,64,S] (LDS tiled) ----------------
__global__ __launch_bounds__(256) void v_transpose(const u16* __restrict__ qkv, u16* __restrict__ Vt) {
  __shared__ u16 tile[256][64];  // 32KB
  const int bh = blockIdx.y;
  const int b = bh >> 4, h = bh & 15;
  const int s0 = blockIdx.x * 256;
  const int tid = threadIdx.x;
  {
    const int c = tid & 7;   // 16B chunk within the 128B d-row
    const int r = tid >> 3;  // 0..31
#pragma unroll
    for (int p = 0; p < 8; ++p) {
      int s = r + p * 32;
      const u16* src = qkv + ((size_t)((b << 11) + s0 + s)) * 3072 + 2048 + h * 64 + c * 8;
      *(uint4*)&tile[s][c * 8] = *(const uint4*)src;
    }
  }
  __syncthreads();
  {
    const int c = tid & 31;  // s chunk (8 elements each)
    const int r = tid >> 5;  // 0..7
#pragma unroll
    for (int p = 0; p < 8; ++p) {
      int d = r + p * 8;
      u16 tmp[8];
#pragma unroll
      for (int j = 0; j < 8; ++j) tmp[j] = tile[c * 8 + j][d];
      u16* dst = Vt + ((size_t)bh * 64 + d) * 2048 + s0 + c * 8;
      *(uint4*)dst = *(uint4*)tmp;
    }
  }
}

// ---------------- causal flash attention: 1 wave per 16 q-rows ----------------
// Qr,Kr [B,H,S,64]; Vt [B,H,64,S]; Ao [B,S,1024] bf16
__global__ __launch_bounds__(64) void attn(const u16* __restrict__ Qr, const u16* __restrict__ Kr,
                                           const u16* __restrict__ Vt, u16* __restrict__ Ao) {
  __shared__ u16 Plds[16 * 32];
  const int lane = threadIdx.x;
  const int bh = blockIdx.y;
  const int q0 = blockIdx.x * 16;
  const u16* Qp = Qr + ((size_t)bh << 11) * 64;
  const u16* Kp = Kr + ((size_t)bh << 11) * 64;
  const u16* Vp = Vt + ((size_t)bh << 11) * 64;  // [64][2048]
  const int fr = lane & 15, fg = lane >> 4;

  short8 aq0 = *(const short8*)(Qp + (q0 + fr) * 64 + fg * 8);
  short8 aq1 = *(const short8*)(Qp + (q0 + fr) * 64 + 32 + fg * 8);

  f32x4 o[4];
#pragma unroll
  for (int n = 0; n < 4; ++n) o[n] = (f32x4){0.f, 0.f, 0.f, 0.f};
  float mrow[4], lrow[4];
#pragma unroll
  for (int r = 0; r < 4; ++r) { mrow[r] = -1e30f; lrow[r] = 0.f; }

  const int nkt = (q0 + 47) >> 5;  // covers keys 0 .. q0+15
  for (int kt = 0; kt < nkt; ++kt) {
    const int kb = kt * 32;
    f32x4 c[2];
#pragma unroll
    for (int n0 = 0; n0 < 2; ++n0) {
      short8 bk0 = *(const short8*)(Kp + (kb + n0 * 16 + fr) * 64 + fg * 8);
      short8 bk1 = *(const short8*)(Kp + (kb + n0 * 16 + fr) * 64 + 32 + fg * 8);
      f32x4 t = (f32x4){0.f, 0.f, 0.f, 0.f};
      t = __builtin_amdgcn_mfma_f32_16x16x32_bf16(aq0, bk0, t, 0, 0, 0);
      t = __builtin_amdgcn_mfma_f32_16x16x32_bf16(aq1, bk1, t, 0, 0, 0);
      c[n0] = t;
    }
    // scale + causal mask
    float pm[2][4];
#pragma unroll
    for (int n0 = 0; n0 < 2; ++n0)
#pragma unroll
      for (int r = 0; r < 4; ++r) {
        int ki = kb + n0 * 16 + fr;
        int qi = q0 + fg * 4 + r;
        float v = c[n0][r] * 0.125f;  // 1/sqrt(64)
        pm[n0][r] = (ki <= qi) ? v : -1e30f;
      }
    // online softmax: row reduce over 16 lanes of the fg-group
    float tmax[4];
#pragma unroll
    for (int r = 0; r < 4; ++r) tmax[r] = fmaxf(pm[0][r], pm[1][r]);
#pragma unroll
    for (int off = 1; off < 16; off <<= 1)
#pragma unroll
      for (int r = 0; r < 4; ++r) tmax[r] = fmaxf(tmax[r], __shfl_xor(tmax[r], off));
    float alpha[4];
#pragma unroll
    for (int r = 0; r < 4; ++r) {
      float nm = fmaxf(mrow[r], tmax[r]);
      alpha[r] = __expf(mrow[r] - nm);
      mrow[r] = nm;
    }
    float ps[2][4];
#pragma unroll
    for (int n0 = 0; n0 < 2; ++n0)
#pragma unroll
      for (int r = 0; r < 4; ++r) ps[n0][r] = __expf(pm[n0][r] - mrow[r]);
    float tsum[4];
#pragma unroll
    for (int r = 0; r < 4; ++r) tsum[r] = ps[0][r] + ps[1][r];
#pragma unroll
    for (int off = 1; off < 16; off <<= 1)
#pragma unroll
      for (int r = 0; r < 4; ++r) tsum[r] += __shfl_xor(tsum[r], off);
#pragma unroll
    for (int r = 0; r < 4; ++r) lrow[r] = lrow[r] * alpha[r] + tsum[r];
#pragma unroll
    for (int n = 0; n < 4; ++n)
#pragma unroll
      for (int r = 0; r < 4; ++r) o[n][r] *= alpha[r];
    // P -> LDS (transpose to A-fragment layout)
#pragma unroll
    for (int n0 = 0; n0 < 2; ++n0)
#pragma unroll
      for (int r = 0; r < 4; ++r)
        Plds[(fg * 4 + r) * 32 + n0 * 16 + fr] = f2bf(ps[n0][r]);
    __syncthreads();
    short8 ap = *(const short8*)(Plds + fr * 32 + fg * 8);
#pragma unroll
    for (int n = 0; n < 4; ++n) {
      short8 bv = *(const short8*)(Vp + (n * 16 + fr) * 2048 + kb + fg * 8);
      o[n] = __builtin_amdgcn_mfma_f32_16x16x32_bf16(ap, bv, o[n], 0, 0, 0);
    }
    __syncthreads();
  }
  const int b = bh >> 4, h = bh & 15;
#pragma unroll
  for (int r = 0; r < 4; ++r) {
    float inv = 1.0f / lrow[r];
    int row = (b << 11) + q0 + fg * 4 + r;
#pragma unroll
    for (int n = 0; n < 4; ++n)
      Ao[(size_t)row * 1024 + h * 64 + n * 16 + fr] = f2bf(o[n][r] * inv);
  }
}

extern "C" void kernel_launch(void* const* d_in, const int* in_sizes, int n_in,
                              void* d_out, int out_size, void* d_ws, size_t ws_size,
                              hipStream_t stream) {
  const float* x = (const float*)d_in[0];
  const int* pos = (const int*)d_in[1];
  const float* Wqkv = (const float*)d_in[2];
  const float* Wo = (const float*)d_in[3];
  float* out = (float*)d_out;

  char* ws = (char*)d_ws;
  const size_t MB = 1024 * 1024;
  u16* xb     = (u16*)(ws);             //  8 MB: [4096,1024]
  u16* wqkvb  = (u16*)(ws + 8 * MB);    //  6 MB: [3072,1024]
  u16* wob    = (u16*)(ws + 14 * MB);   //  2 MB: [1024,1024]
  u16* qkv    = (u16*)(ws + 16 * MB);   // 24 MB: [4096,3072]
  u16* Qr     = (u16*)(ws + 40 * MB);   //  8 MB: [B,H,S,64]
  u16* Kr     = (u16*)(ws + 48 * MB);   //  8 MB
  u16* Vt     = (u16*)(ws + 56 * MB);   //  8 MB: [B,H,64,S]
  u16* ao     = (u16*)(ws + 64 * MB);   //  8 MB: [4096,1024]

  // 1) converts
  cvt_f32_bf16<<<4096, 256, 0, stream>>>(x, xb, 4194304 / 4);
  cvt_f32_bf16<<<3072, 256, 0, stream>>>(Wqkv, wqkvb, 3145728 / 4);
  cvt_f32_bf16<<<1024, 256, 0, stream>>>(Wo, wob, 1048576 / 4);
  // 2) QKV projection
  gemm_bt<u16><<<dim3(32, 24), 256, 0, stream>>>(xb, wqkvb, qkv, 4096, 3072, 1024);
  // 3) RoPE + layouts
  rope_qk<<<8192, 256, 0, stream>>>(qkv, pos, Qr, Kr);
  v_transpose<<<dim3(8, 32), 256, 0, stream>>>(qkv, Vt);
  // 4) attention
  attn<<<dim3(128, 32), 64, 0, stream>>>(Qr, Kr, Vt, ao);
  // 5) output projection
  gemm_bt<float><<<dim3(32, 8), 256, 0, stream>>>(ao, wob, out, 4096, 1024, 1024);
}

// Round 2
// 237.518 us; speedup vs baseline: 1.6459x; 1.6459x over previous
//
#include <hip/hip_runtime.h>
#include <hip/hip_bf16.h>

// Problem constants: B=2, S=2048, H=16, dk=64, D_MODEL=1024, THETA=10000

using u16 = unsigned short;
typedef __attribute__((ext_vector_type(8))) short short8;
typedef __attribute__((ext_vector_type(4))) float f32x4;
typedef __attribute__((ext_vector_type(16))) float f32x16;
typedef __attribute__((ext_vector_type(2))) unsigned uint2v;
typedef __attribute__((ext_vector_type(4))) unsigned uint4v;

__device__ __forceinline__ float bf2f(u16 v) {
  unsigned u = ((unsigned)v) << 16; float f; __builtin_memcpy(&f, &u, 4); return f;
}
__device__ __forceinline__ u16 f2bf(float f) {
  unsigned u; __builtin_memcpy(&u, &f, 4);
  return (u16)((u + 0x7fffu + ((u >> 16) & 1u)) >> 16);
}

__device__ __forceinline__ void gload_lds16(const void* g, void* l) {
  __builtin_amdgcn_global_load_lds((const __attribute__((address_space(1))) unsigned*)g,
                                   (__attribute__((address_space(3))) unsigned*)l, 16, 0, 0);
}

// ---------------- fp32 -> bf16 convert (vectorized) ----------------
__global__ __launch_bounds__(256) void cvt_f32_bf16(const float* __restrict__ in,
                                                    u16* __restrict__ out, int n4) {
  int i = blockIdx.x * 256 + threadIdx.x;
  if (i < n4) {
    float4 v = *(const float4*)(in + (size_t)i * 4);
    unsigned lo = f2bf(v.x) | ((unsigned)f2bf(v.y) << 16);
    unsigned hi = f2bf(v.z) | ((unsigned)f2bf(v.w) << 16);
    uint2 w; w.x = lo; w.y = hi;
    *(uint2*)(out + (size_t)i * 4) = w;
  }
}

// ---------------- GEMM: C[M,N] = A[M,K] * B[N,K]^T, bf16 in, fp32 acc ----------------
template <typename OutT>
__global__ __launch_bounds__(256) void gemm_bt(const u16* __restrict__ A, const u16* __restrict__ B,
                                               OutT* __restrict__ C, int M, int N, int K) {
  __shared__ u16 As[128 * 32];
  __shared__ u16 Bs[128 * 32];
  const int tid = threadIdx.x;
  const int wave = tid >> 6;
  const int lane = tid & 63;
  const int m0 = blockIdx.x * 128;
  const int n0 = blockIdx.y * 128;
  const int wm = (wave >> 1) * 64;
  const int wn = (wave & 1) * 64;

  f32x4 acc[4][4];
#pragma unroll
  for (int m = 0; m < 4; ++m)
#pragma unroll
    for (int n = 0; n < 4; ++n) acc[m][n] = (f32x4){0.f, 0.f, 0.f, 0.f};

  const int srow = lane >> 2;
  const int scol = (lane & 3) * 8;
  const u16* Ag0 = A + (size_t)(m0 + wave * 16 + srow) * K + scol;
  const u16* Ag1 = A + (size_t)(m0 + 64 + wave * 16 + srow) * K + scol;
  const u16* Bg0 = B + (size_t)(n0 + wave * 16 + srow) * K + scol;
  const u16* Bg1 = B + (size_t)(n0 + 64 + wave * 16 + srow) * K + scol;
  u16* AsW0 = As + (wave * 16) * 32;
  u16* AsW1 = As + (64 + wave * 16) * 32;
  u16* BsW0 = Bs + (wave * 16) * 32;
  u16* BsW1 = Bs + (64 + wave * 16) * 32;

  const int fr = lane & 15;
  const int fk = (lane >> 4) * 8;

  for (int k0 = 0; k0 < K; k0 += 32) {
    __syncthreads();
    gload_lds16(Ag0 + k0, AsW0);
    gload_lds16(Ag1 + k0, AsW1);
    gload_lds16(Bg0 + k0, BsW0);
    gload_lds16(Bg1 + k0, BsW1);
    __syncthreads();

    short8 af[4], bf[4];
#pragma unroll
    for (int m = 0; m < 4; ++m)
      af[m] = *(const short8*)(As + (wm + m * 16 + fr) * 32 + fk);
#pragma unroll
    for (int n = 0; n < 4; ++n)
      bf[n] = *(const short8*)(Bs + (wn + n * 16 + fr) * 32 + fk);
#pragma unroll
    for (int m = 0; m < 4; ++m)
#pragma unroll
      for (int n = 0; n < 4; ++n)
        acc[m][n] = __builtin_amdgcn_mfma_f32_16x16x32_bf16(af[m], bf[n], acc[m][n], 0, 0, 0);
  }

  const int fg = lane >> 4;
#pragma unroll
  for (int m = 0; m < 4; ++m)
#pragma unroll
    for (int n = 0; n < 4; ++n)
#pragma unroll
      for (int r = 0; r < 4; ++r) {
        int row = m0 + wm + m * 16 + fg * 4 + r;
        int col = n0 + wn + n * 16 + fr;
        if constexpr (sizeof(OutT) == 2)
          C[(size_t)row * N + col] = (OutT)f2bf(acc[m][n][r]);
        else
          C[(size_t)row * N + col] = (OutT)acc[m][n][r];
      }
}

// ---------------- RoPE on Q,K: qkv[B,S,3072] -> Qr,Kr [B,H,S,64]; Q pre-scaled 1/8 ----------------
__global__ __launch_bounds__(256) void rope_qk(const u16* __restrict__ qkv, const int* __restrict__ pos,
                                               u16* __restrict__ Qr, u16* __restrict__ Kr) {
  int t = blockIdx.x * 256 + threadIdx.x;
  int i = t & 31;
  int h = (t >> 5) & 15;
  int s = (t >> 9) & 2047;
  int b = t >> 20;
  float p = (float)pos[(b << 11) + s];
  float ang = p * __builtin_exp2f(-(float)i * 0.41524101186f);
  float sn, cs;
  sincosf(ang, &sn, &cs);
  const u16* base = qkv + ((size_t)((b << 11) + s)) * 3072 + h * 64 + 2 * i;
  float qe = bf2f(base[0]), qo = bf2f(base[1]);
  float ke = bf2f(base[1024]), ko = bf2f(base[1025]);
  size_t o = (((size_t)((b << 4) + h) << 11) + s) * 64 + 2 * i;
  // Q pre-scaled by 1/sqrt(dk)=0.125 (exact pow2, no bf16 precision loss)
  unsigned qw = f2bf((cs * qe - sn * qo) * 0.125f) | ((unsigned)f2bf((sn * qe + cs * qo) * 0.125f) << 16);
  unsigned kw = f2bf(cs * ke - sn * ko) | ((unsigned)f2bf(sn * ke + cs * ko) << 16);
  *(unsigned*)(Qr + o) = qw;
  *(unsigned*)(Kr + o) = kw;
}

// ---------------- V transpose: qkv V-part -> Vt [B,H,64,S] ----------------
__global__ __launch_bounds__(256) void v_transpose(const u16* __restrict__ qkv, u16* __restrict__ Vt) {
  __shared__ u16 tile[256][64];
  const int bh = blockIdx.y;
  const int b = bh >> 4, h = bh & 15;
  const int s0 = blockIdx.x * 256;
  const int tid = threadIdx.x;
  {
    const int c = tid & 7;
    const int r = tid >> 3;
#pragma unroll
    for (int p = 0; p < 8; ++p) {
      int s = r + p * 32;
      const u16* src = qkv + ((size_t)((b << 11) + s0 + s)) * 3072 + 2048 + h * 64 + c * 8;
      *(uint4*)&tile[s][c * 8] = *(const uint4*)src;
    }
  }
  __syncthreads();
  {
    const int c = tid & 31;
    const int r = tid >> 5;
#pragma unroll
    for (int p = 0; p < 8; ++p) {
      int d = r + p * 8;
      u16 tmp[8];
#pragma unroll
      for (int j = 0; j < 8; ++j) tmp[j] = tile[c * 8 + j][d];
      u16* dst = Vt + ((size_t)bh * 64 + d) * 2048 + s0 + c * 8;
      *(uint4*)dst = *(uint4*)tmp;
    }
  }
}

// ---------------- causal flash attention, swapped-QK^T 32x32 structure ----------------
// One wave per 32 q-rows. S=mfma(K,Q): lane owns q=lane&31, 16 keys in regs.
// Softmax in-register; P -> PV B-operand via cvt_pk + permlane32_swap. No LDS.
__global__ __launch_bounds__(64) void attn2(const u16* __restrict__ Qr, const u16* __restrict__ Kr,
                                            const u16* __restrict__ Vt, u16* __restrict__ Ao) {
  const int lane = threadIdx.x;
  const int bid = blockIdx.x;            // 2048 = 8 xcd * 4 bh * 64 qt
  const int xcd = bid & 7;
  const int rr = bid >> 3;
  const int bh = xcd * 4 + (rr & 3);     // 4 bh per XCD -> K/V set 2MB, L2-fits
  const int qt = 63 - (rr >> 2);         // heavy tiles dispatched first
  const int q0 = qt * 32;
  const u16* __restrict__ Qp = Qr + ((size_t)bh << 11) * 64;
  const u16* __restrict__ Kp = Kr + ((size_t)bh << 11) * 64;
  const u16* __restrict__ Vp = Vt + ((size_t)bh << 11) * 64;  // [64][2048]
  const int lq = lane & 31;
  const int hi = lane >> 5;

  // Q as B-operand: lane holds Q[q0+lq, j*16 + hi*8 .. +8] per MFMA j
  short8 qf[4];
#pragma unroll
  for (int j = 0; j < 4; ++j)
    qf[j] = *(const short8*)(Qp + (size_t)(q0 + lq) * 64 + j * 16 + hi * 8);

  f32x16 o0, o1;
#pragma unroll
  for (int r = 0; r < 16; ++r) { o0[r] = 0.f; o1[r] = 0.f; }
  float m = -1e30f, lsum = 0.f;

  for (int kt = 0; kt <= qt; ++kt) {
    const int kb = kt * 32;
    // K as A-operand: lane holds K[kb+lq, j*16 + hi*8 ..]
    short8 kf0 = *(const short8*)(Kp + (size_t)(kb + lq) * 64 + 0 + hi * 8);
    short8 kf1 = *(const short8*)(Kp + (size_t)(kb + lq) * 64 + 16 + hi * 8);
    short8 kf2 = *(const short8*)(Kp + (size_t)(kb + lq) * 64 + 32 + hi * 8);
    short8 kf3 = *(const short8*)(Kp + (size_t)(kb + lq) * 64 + 48 + hi * 8);

    f32x16 sc;
#pragma unroll
    for (int r = 0; r < 16; ++r) sc[r] = 0.f;
    sc = __builtin_amdgcn_mfma_f32_32x32x16_bf16(kf0, qf[0], sc, 0, 0, 0);
    sc = __builtin_amdgcn_mfma_f32_32x32x16_bf16(kf1, qf[1], sc, 0, 0, 0);
    sc = __builtin_amdgcn_mfma_f32_32x32x16_bf16(kf2, qf[2], sc, 0, 0, 0);
    sc = __builtin_amdgcn_mfma_f32_32x32x16_bf16(kf3, qf[3], sc, 0, 0, 0);

    // V^T A-frags issued early to hide L2 latency under softmax
    short8 vf00 = *(const short8*)(Vp + (size_t)(lq) * 2048 + kb + 0 + hi * 8);
    short8 vf01 = *(const short8*)(Vp + (size_t)(lq) * 2048 + kb + 16 + hi * 8);
    short8 vf10 = *(const short8*)(Vp + (size_t)(32 + lq) * 2048 + kb + 0 + hi * 8);
    short8 vf11 = *(const short8*)(Vp + (size_t)(32 + lq) * 2048 + kb + 16 + hi * 8);

    if (kt == qt) {  // diagonal tile: causal mask (wave-uniform branch)
#pragma unroll
      for (int r = 0; r < 16; ++r) {
        int ko = (r & 3) + 8 * (r >> 2) + 4 * hi;
        sc[r] = (ko <= lq) ? sc[r] : -1e30f;
      }
    }

    // row max: in-lane tree over 16 regs + one cross-half exchange
    float red[16];
#pragma unroll
    for (int r = 0; r < 16; ++r) red[r] = sc[r];
#pragma unroll
    for (int s = 8; s >= 1; s >>= 1)
#pragma unroll
      for (int r = 0; r < s; ++r) red[r] = fmaxf(red[r], red[r + s]);
    float pmax = red[0];
    pmax = fmaxf(pmax, __shfl_xor(pmax, 32));
    float nm = fmaxf(m, pmax);
    float alpha = __expf(m - nm);
    m = nm;

    float ps[16];
#pragma unroll
    for (int r = 0; r < 16; ++r) ps[r] = __expf(sc[r] - nm);
#pragma unroll
    for (int r = 0; r < 16; ++r) red[r] = ps[r];
#pragma unroll
    for (int s = 8; s >= 1; s >>= 1)
#pragma unroll
      for (int r = 0; r < s; ++r) red[r] += red[r + s];
    float tsum = red[0];
    tsum += __shfl_xor(tsum, 32);
    lsum = lsum * alpha + tsum;
#pragma unroll
    for (int r = 0; r < 16; ++r) { o0[r] *= alpha; o1[r] *= alpha; }

    // P -> bf16 B-operand: cvt_pk pairs, permlane32_swap group g with g+1
    unsigned w[8];
#pragma unroll
    for (int t = 0; t < 8; ++t) {
      unsigned d;
      asm("v_cvt_pk_bf16_f32 %0, %1, %2" : "=v"(d) : "v"(ps[2 * t]), "v"(ps[2 * t + 1]));
      w[t] = d;
    }
    short8 pb[2];
#pragma unroll
    for (int j = 0; j < 2; ++j) {
      uint2v r1 = __builtin_amdgcn_permlane32_swap(w[4 * j + 0], w[4 * j + 2], false, false);
      uint2v r2 = __builtin_amdgcn_permlane32_swap(w[4 * j + 1], w[4 * j + 3], false, false);
      uint4v t4;
      t4.x = r1.x; t4.y = r2.x; t4.z = r1.y; t4.w = r2.y;
      pb[j] = __builtin_bit_cast(short8, t4);
    }

    o0 = __builtin_amdgcn_mfma_f32_32x32x16_bf16(vf00, pb[0], o0, 0, 0, 0);
    o0 = __builtin_amdgcn_mfma_f32_32x32x16_bf16(vf01, pb[1], o0, 0, 0, 0);
    o1 = __builtin_amdgcn_mfma_f32_32x32x16_bf16(vf10, pb[0], o1, 0, 0, 0);
    o1 = __builtin_amdgcn_mfma_f32_32x32x16_bf16(vf11, pb[1], o1, 0, 0, 0);
  }

  // epilogue: O^T[d, q] -> Ao[b, q, h*64+d], 4 consecutive d per reg-group
  float inv = 1.f / lsum;
  const int b = bh >> 4, h = bh & 15;
  u16* outp = Ao + ((size_t)(b << 11) + q0 + lq) * 1024 + h * 64;
#pragma unroll
  for (int g = 0; g < 4; ++g) {
    int d = 8 * g + 4 * hi;
    uint2v w0;
    w0.x = f2bf(o0[4 * g + 0] * inv) | ((unsigned)f2bf(o0[4 * g + 1] * inv) << 16);
    w0.y = f2bf(o0[4 * g + 2] * inv) | ((unsigned)f2bf(o0[4 * g + 3] * inv) << 16);
    *(uint2v*)(outp + d) = w0;
    uint2v w1;
    w1.x = f2bf(o1[4 * g + 0] * inv) | ((unsigned)f2bf(o1[4 * g + 1] * inv) << 16);
    w1.y = f2bf(o1[4 * g + 2] * inv) | ((unsigned)f2bf(o1[4 * g + 3] * inv) << 16);
    *(uint2v*)(outp + 32 + d) = w1;
  }
}

extern "C" void kernel_launch(void* const* d_in, const int* in_sizes, int n_in,
                              void* d_out, int out_size, void* d_ws, size_t ws_size,
                              hipStream_t stream) {
  const float* x = (const float*)d_in[0];
  const int* pos = (const int*)d_in[1];
  const float* Wqkv = (const float*)d_in[2];
  const float* Wo = (const float*)d_in[3];
  float* out = (float*)d_out;

  char* ws = (char*)d_ws;
  const size_t MB = 1024 * 1024;
  u16* xb     = (u16*)(ws);             //  8 MB: [4096,1024]
  u16* wqkvb  = (u16*)(ws + 8 * MB);    //  6 MB: [3072,1024]
  u16* wob    = (u16*)(ws + 14 * MB);   //  2 MB: [1024,1024]
  u16* qkv    = (u16*)(ws + 16 * MB);   // 24 MB: [4096,3072]
  u16* Qr     = (u16*)(ws + 40 * MB);   //  8 MB: [B,H,S,64] (pre-scaled 1/8)
  u16* Kr     = (u16*)(ws + 48 * MB);   //  8 MB
  u16* Vt     = (u16*)(ws + 56 * MB);   //  8 MB: [B,H,64,S]
  u16* ao     = (u16*)(ws + 64 * MB);   //  8 MB: [4096,1024]

  cvt_f32_bf16<<<4096, 256, 0, stream>>>(x, xb, 4194304 / 4);
  cvt_f32_bf16<<<3072, 256, 0, stream>>>(Wqkv, wqkvb, 3145728 / 4);
  cvt_f32_bf16<<<1024, 256, 0, stream>>>(Wo, wob, 1048576 / 4);
  gemm_bt<u16><<<dim3(32, 24), 256, 0, stream>>>(xb, wqkvb, qkv, 4096, 3072, 1024);
  rope_qk<<<8192, 256, 0, stream>>>(qkv, pos, Qr, Kr);
  v_transpose<<<dim3(8, 32), 256, 0, stream>>>(qkv, Vt);
  attn2<<<2048, 64, 0, stream>>>(Qr, Kr, Vt, ao);
  gemm_bt<float><<<dim3(32, 8), 256, 0, stream>>>(ao, wob, out, 4096, 1024, 1024);
}

// Round 3
// 230.947 us; speedup vs baseline: 1.6928x; 1.0285x over previous
//
#include <hip/hip_runtime.h>
#include <hip/hip_bf16.h>

// Problem constants: B=2, S=2048, H=16, dk=64, D_MODEL=1024, THETA=10000

using u16 = unsigned short;
typedef __attribute__((ext_vector_type(8))) short short8;
typedef __attribute__((ext_vector_type(4))) float f32x4;
typedef __attribute__((ext_vector_type(16))) float f32x16;
typedef __attribute__((ext_vector_type(2))) unsigned uint2v;
typedef __attribute__((ext_vector_type(4))) unsigned uint4v;

__device__ __forceinline__ float bf2f(u16 v) {
  unsigned u = ((unsigned)v) << 16; float f; __builtin_memcpy(&f, &u, 4); return f;
}
__device__ __forceinline__ u16 f2bf(float f) {
  unsigned u; __builtin_memcpy(&u, &f, 4);
  return (u16)((u + 0x7fffu + ((u >> 16) & 1u)) >> 16);
}

__device__ __forceinline__ void gload_lds16(const void* g, void* l) {
  __builtin_amdgcn_global_load_lds((const __attribute__((address_space(1))) unsigned*)g,
                                   (__attribute__((address_space(3))) unsigned*)l, 16, 0, 0);
}

// ---------------- fused fp32 -> bf16 convert for x, W_qkv, W_o ----------------
__global__ __launch_bounds__(256) void cvt_all(const float* __restrict__ x, const float* __restrict__ wqkv,
                                               const float* __restrict__ wo, u16* __restrict__ xb,
                                               u16* __restrict__ wqkvb, u16* __restrict__ wob) {
  int i = blockIdx.x * 256 + threadIdx.x;  // 2M quads total
  const float* src; u16* dst; int off;
  if (i < 1048576) { src = x; dst = xb; off = i; }
  else if (i < 1048576 + 786432) { src = wqkv; dst = wqkvb; off = i - 1048576; }
  else { src = wo; dst = wob; off = i - (1048576 + 786432); }
  float4 v = *(const float4*)(src + (size_t)off * 4);
  unsigned lo = f2bf(v.x) | ((unsigned)f2bf(v.y) << 16);
  unsigned hi = f2bf(v.z) | ((unsigned)f2bf(v.w) << 16);
  uint2 w; w.x = lo; w.y = hi;
  *(uint2*)(dst + (size_t)off * 4) = w;
}

// ---------------- GEMM: C[M,N] = A[M,K] * B[N,K]^T, bf16 in, fp32 acc ----------------
template <typename OutT>
__global__ __launch_bounds__(256) void gemm_bt(const u16* __restrict__ A, const u16* __restrict__ B,
                                               OutT* __restrict__ C, int M, int N, int K) {
  __shared__ u16 As[128 * 32];
  __shared__ u16 Bs[128 * 32];
  const int tid = threadIdx.x;
  const int wave = tid >> 6;
  const int lane = tid & 63;
  const int m0 = blockIdx.x * 128;
  const int n0 = blockIdx.y * 128;
  const int wm = (wave >> 1) * 64;
  const int wn = (wave & 1) * 64;

  f32x4 acc[4][4];
#pragma unroll
  for (int m = 0; m < 4; ++m)
#pragma unroll
    for (int n = 0; n < 4; ++n) acc[m][n] = (f32x4){0.f, 0.f, 0.f, 0.f};

  const int srow = lane >> 2;
  const int scol = (lane & 3) * 8;
  const u16* Ag0 = A + (size_t)(m0 + wave * 16 + srow) * K + scol;
  const u16* Ag1 = A + (size_t)(m0 + 64 + wave * 16 + srow) * K + scol;
  const u16* Bg0 = B + (size_t)(n0 + wave * 16 + srow) * K + scol;
  const u16* Bg1 = B + (size_t)(n0 + 64 + wave * 16 + srow) * K + scol;
  u16* AsW0 = As + (wave * 16) * 32;
  u16* AsW1 = As + (64 + wave * 16) * 32;
  u16* BsW0 = Bs + (wave * 16) * 32;
  u16* BsW1 = Bs + (64 + wave * 16) * 32;

  const int fr = lane & 15;
  const int fk = (lane >> 4) * 8;

  for (int k0 = 0; k0 < K; k0 += 32) {
    __syncthreads();
    gload_lds16(Ag0 + k0, AsW0);
    gload_lds16(Ag1 + k0, AsW1);
    gload_lds16(Bg0 + k0, BsW0);
    gload_lds16(Bg1 + k0, BsW1);
    __syncthreads();

    short8 af[4], bf[4];
#pragma unroll
    for (int m = 0; m < 4; ++m)
      af[m] = *(const short8*)(As + (wm + m * 16 + fr) * 32 + fk);
#pragma unroll
    for (int n = 0; n < 4; ++n)
      bf[n] = *(const short8*)(Bs + (wn + n * 16 + fr) * 32 + fk);
#pragma unroll
    for (int m = 0; m < 4; ++m)
#pragma unroll
      for (int n = 0; n < 4; ++n)
        acc[m][n] = __builtin_amdgcn_mfma_f32_16x16x32_bf16(af[m], bf[n], acc[m][n], 0, 0, 0);
  }

  const int fg = lane >> 4;
#pragma unroll
  for (int m = 0; m < 4; ++m)
#pragma unroll
    for (int n = 0; n < 4; ++n)
#pragma unroll
      for (int r = 0; r < 4; ++r) {
        int row = m0 + wm + m * 16 + fg * 4 + r;
        int col = n0 + wn + n * 16 + fr;
        if constexpr (sizeof(OutT) == 2)
          C[(size_t)row * N + col] = (OutT)f2bf(acc[m][n][r]);
        else
          C[(size_t)row * N + col] = (OutT)acc[m][n][r];
      }
}

// ---------------- RoPE on Q,K: qkv[B,S,3072] -> Qr,Kr [B,H,S,64]; Q pre-scaled 1/8 ----------------
__global__ __launch_bounds__(256) void rope_qk(const u16* __restrict__ qkv, const int* __restrict__ pos,
                                               u16* __restrict__ Qr, u16* __restrict__ Kr) {
  int t = blockIdx.x * 256 + threadIdx.x;
  int i = t & 31;
  int h = (t >> 5) & 15;
  int s = (t >> 9) & 2047;
  int b = t >> 20;
  float p = (float)pos[(b << 11) + s];
  float ang = p * __builtin_exp2f(-(float)i * 0.41524101186f);
  float sn, cs;
  sincosf(ang, &sn, &cs);
  const u16* base = qkv + ((size_t)((b << 11) + s)) * 3072 + h * 64 + 2 * i;
  float qe = bf2f(base[0]), qo = bf2f(base[1]);
  float ke = bf2f(base[1024]), ko = bf2f(base[1025]);
  size_t o = (((size_t)((b << 4) + h) << 11) + s) * 64 + 2 * i;
  unsigned qw = f2bf((cs * qe - sn * qo) * 0.125f) | ((unsigned)f2bf((sn * qe + cs * qo) * 0.125f) << 16);
  unsigned kw = f2bf(cs * ke - sn * ko) | ((unsigned)f2bf(sn * ke + cs * ko) << 16);
  *(unsigned*)(Qr + o) = qw;
  *(unsigned*)(Kr + o) = kw;
}

// ---------------- V transpose: qkv V-part -> Vt [B,H,64,S] ----------------
__global__ __launch_bounds__(256) void v_transpose(const u16* __restrict__ qkv, u16* __restrict__ Vt) {
  __shared__ u16 tile[256][64];
  const int bh = blockIdx.y;
  const int b = bh >> 4, h = bh & 15;
  const int s0 = blockIdx.x * 256;
  const int tid = threadIdx.x;
  {
    const int c = tid & 7;
    const int r = tid >> 3;
#pragma unroll
    for (int p = 0; p < 8; ++p) {
      int s = r + p * 32;
      const u16* src = qkv + ((size_t)((b << 11) + s0 + s)) * 3072 + 2048 + h * 64 + c * 8;
      *(uint4*)&tile[s][c * 8] = *(const uint4*)src;
    }
  }
  __syncthreads();
  {
    const int c = tid & 31;
    const int r = tid >> 5;
#pragma unroll
    for (int p = 0; p < 8; ++p) {
      int d = r + p * 8;
      u16 tmp[8];
#pragma unroll
      for (int j = 0; j < 8; ++j) tmp[j] = tile[c * 8 + j][d];
      u16* dst = Vt + ((size_t)bh * 64 + d) * 2048 + s0 + c * 8;
      *(uint4*)dst = *(uint4*)tmp;
    }
  }
}

// ---------------- causal flash attention v3 ----------------
// 2 waves per block, one 32-row q-tile per block; wave w handles key-tile range
// [w*ceil(n/2), ...). Swapped QK^T (32x32x16), in-register softmax with
// defer-max (THR=8), P via cvt_pk+permlane32_swap, merge partials through LDS.
__global__ __launch_bounds__(128, 4) void attn3(const u16* __restrict__ Qr, const u16* __restrict__ Kr,
                                                const u16* __restrict__ Vt, u16* __restrict__ Ao) {
  __shared__ float smM[64], smL[64];
  __shared__ float smO[64][33];  // +1 pad: lane-major writes 2-way not 32-way
  const int tid = threadIdx.x;
  const int lane = tid & 63;
  const int wid = tid >> 6;
  const int bid = blockIdx.x;            // 2048 = 8 xcd * 4 bh * 64 qt
  const int xcd = bid & 7;
  const int rr = bid >> 3;
  const int bh = xcd * 4 + (rr & 3);     // 4 bh per XCD -> K/V 2MB, L2-fits
  const int qt = 63 - (rr >> 2);         // heavy q-tiles dispatched first
  const int q0 = qt * 32;
  const u16* __restrict__ Qp = Qr + ((size_t)bh << 11) * 64;
  const u16* __restrict__ Kp = Kr + ((size_t)bh << 11) * 64;
  const u16* __restrict__ Vp = Vt + ((size_t)bh << 11) * 64;  // [64][2048]
  const int lq = lane & 31;
  const int hi = lane >> 5;

  short8 qf0 = *(const short8*)(Qp + (size_t)(q0 + lq) * 64 + 0 + hi * 8);
  short8 qf1 = *(const short8*)(Qp + (size_t)(q0 + lq) * 64 + 16 + hi * 8);
  short8 qf2 = *(const short8*)(Qp + (size_t)(q0 + lq) * 64 + 32 + hi * 8);
  short8 qf3 = *(const short8*)(Qp + (size_t)(q0 + lq) * 64 + 48 + hi * 8);

  f32x16 o0, o1;
#pragma unroll
  for (int r = 0; r < 16; ++r) { o0[r] = 0.f; o1[r] = 0.f; }
  float m = -1e30f, lsum = 0.f;

  const int nkt = qt + 1;
  const int half = (nkt + 1) >> 1;
  const int ktbeg = wid ? half : 0;
  const int ktend = wid ? nkt : half;

  for (int kt = ktbeg; kt < ktend; ++kt) {
    const int kb = kt << 5;
    const u16* kp = Kp + (size_t)(kb + lq) * 64 + hi * 8;
    short8 kf0 = *(const short8*)(kp);
    short8 kf1 = *(const short8*)(kp + 16);
    short8 kf2 = *(const short8*)(kp + 32);
    short8 kf3 = *(const short8*)(kp + 48);
    const u16* vp = Vp + (size_t)lq * 2048 + kb + hi * 8;
    short8 vf00 = *(const short8*)(vp);
    short8 vf01 = *(const short8*)(vp + 16);
    short8 vf10 = *(const short8*)(vp + (size_t)32 * 2048);
    short8 vf11 = *(const short8*)(vp + (size_t)32 * 2048 + 16);

    f32x16 sc;
#pragma unroll
    for (int r = 0; r < 16; ++r) sc[r] = 0.f;
    sc = __builtin_amdgcn_mfma_f32_32x32x16_bf16(kf0, qf0, sc, 0, 0, 0);
    sc = __builtin_amdgcn_mfma_f32_32x32x16_bf16(kf1, qf1, sc, 0, 0, 0);
    sc = __builtin_amdgcn_mfma_f32_32x32x16_bf16(kf2, qf2, sc, 0, 0, 0);
    sc = __builtin_amdgcn_mfma_f32_32x32x16_bf16(kf3, qf3, sc, 0, 0, 0);

    if (kt == qt) {  // diagonal tile: causal mask
#pragma unroll
      for (int r = 0; r < 16; ++r) {
        int ko = (r & 3) + 8 * (r >> 2) + 4 * hi;
        sc[r] = (ko <= lq) ? sc[r] : -1e30f;
      }
    }

    // row max: 8 temps + tree + cross-half
    float r8[8];
#pragma unroll
    for (int r = 0; r < 8; ++r) r8[r] = fmaxf(sc[r], sc[r + 8]);
#pragma unroll
    for (int s = 4; s >= 1; s >>= 1)
#pragma unroll
      for (int r = 0; r < s; ++r) r8[r] = fmaxf(r8[r], r8[r + s]);
    float pmax = fmaxf(r8[0], __shfl_xor(r8[0], 32));

    // defer-max: rescale only when the running max is beaten by >8
    if (!__all(pmax - m <= 8.0f)) {
      float nm = fmaxf(m, pmax);
      float alpha = __expf(m - nm);
      lsum *= alpha;
#pragma unroll
      for (int r = 0; r < 16; ++r) { o0[r] *= alpha; o1[r] *= alpha; }
      m = nm;
    }

    // P = exp(S - m), in place
#pragma unroll
    for (int r = 0; r < 16; ++r) sc[r] = __expf(sc[r] - m);
#pragma unroll
    for (int r = 0; r < 8; ++r) r8[r] = sc[r] + sc[r + 8];
#pragma unroll
    for (int s = 4; s >= 1; s >>= 1)
#pragma unroll
      for (int r = 0; r < s; ++r) r8[r] += r8[r + s];
    lsum += r8[0] + __shfl_xor(r8[0], 32);

    // P -> bf16 B-operand: cvt_pk pairs, permlane32_swap group g with g+2
    unsigned w[8];
#pragma unroll
    for (int t = 0; t < 8; ++t) {
      unsigned d;
      asm("v_cvt_pk_bf16_f32 %0, %1, %2" : "=v"(d) : "v"(sc[2 * t]), "v"(sc[2 * t + 1]));
      w[t] = d;
    }
    short8 pb0, pb1;
    {
      uint2v r1 = __builtin_amdgcn_permlane32_swap(w[0], w[2], false, false);
      uint2v r2 = __builtin_amdgcn_permlane32_swap(w[1], w[3], false, false);
      uint4v t4; t4.x = r1.x; t4.y = r2.x; t4.z = r1.y; t4.w = r2.y;
      pb0 = __builtin_bit_cast(short8, t4);
      uint2v r3 = __builtin_amdgcn_permlane32_swap(w[4], w[6], false, false);
      uint2v r4 = __builtin_amdgcn_permlane32_swap(w[5], w[7], false, false);
      uint4v t5; t5.x = r3.x; t5.y = r4.x; t5.z = r3.y; t5.w = r4.y;
      pb1 = __builtin_bit_cast(short8, t5);
    }

    o0 = __builtin_amdgcn_mfma_f32_32x32x16_bf16(vf00, pb0, o0, 0, 0, 0);
    o0 = __builtin_amdgcn_mfma_f32_32x32x16_bf16(vf01, pb1, o0, 0, 0, 0);
    o1 = __builtin_amdgcn_mfma_f32_32x32x16_bf16(vf10, pb0, o1, 0, 0, 0);
    o1 = __builtin_amdgcn_mfma_f32_32x32x16_bf16(vf11, pb1, o1, 0, 0, 0);
  }

  // merge the two waves' partials
  if (wid == 1) {
    smM[lane] = m;
    smL[lane] = lsum;
#pragma unroll
    for (int r = 0; r < 16; ++r) smO[lane][r] = o0[r];
#pragma unroll
    for (int r = 0; r < 16; ++r) smO[lane][16 + r] = o1[r];
  }
  __syncthreads();
  if (wid == 0) {
    float m1 = smM[lane], l1 = smL[lane];
    float M = fmaxf(m, m1);
    float a0 = __expf(m - M), a1 = __expf(m1 - M);
    float L = lsum * a0 + l1 * a1;
    float inv = 1.f / L;
    const int b = bh >> 4, h = bh & 15;
    u16* outp = Ao + ((size_t)(b << 11) + q0 + lq) * 1024 + h * 64;
#pragma unroll
    for (int g = 0; g < 4; ++g) {
      int d = 8 * g + 4 * hi;
      float c0 = (o0[4 * g + 0] * a0 + smO[lane][4 * g + 0] * a1) * inv;
      float c1 = (o0[4 * g + 1] * a0 + smO[lane][4 * g + 1] * a1) * inv;
      float c2 = (o0[4 * g + 2] * a0 + smO[lane][4 * g + 2] * a1) * inv;
      float c3 = (o0[4 * g + 3] * a0 + smO[lane][4 * g + 3] * a1) * inv;
      uint2v w0;
      w0.x = f2bf(c0) | ((unsigned)f2bf(c1) << 16);
      w0.y = f2bf(c2) | ((unsigned)f2bf(c3) << 16);
      *(uint2v*)(outp + d) = w0;
      float c4 = (o1[4 * g + 0] * a0 + smO[lane][16 + 4 * g + 0] * a1) * inv;
      float c5 = (o1[4 * g + 1] * a0 + smO[lane][16 + 4 * g + 1] * a1) * inv;
      float c6 = (o1[4 * g + 2] * a0 + smO[lane][16 + 4 * g + 2] * a1) * inv;
      float c7 = (o1[4 * g + 3] * a0 + smO[lane][16 + 4 * g + 3] * a1) * inv;
      uint2v w1;
      w1.x = f2bf(c4) | ((unsigned)f2bf(c5) << 16);
      w1.y = f2bf(c6) | ((unsigned)f2bf(c7) << 16);
      *(uint2v*)(outp + 32 + d) = w1;
    }
  }
}

extern "C" void kernel_launch(void* const* d_in, const int* in_sizes, int n_in,
                              void* d_out, int out_size, void* d_ws, size_t ws_size,
                              hipStream_t stream) {
  const float* x = (const float*)d_in[0];
  const int* pos = (const int*)d_in[1];
  const float* Wqkv = (const float*)d_in[2];
  const float* Wo = (const float*)d_in[3];
  float* out = (float*)d_out;

  char* ws = (char*)d_ws;
  const size_t MB = 1024 * 1024;
  u16* xb     = (u16*)(ws);             //  8 MB: [4096,1024]
  u16* wqkvb  = (u16*)(ws + 8 * MB);    //  6 MB: [3072,1024]
  u16* wob    = (u16*)(ws + 14 * MB);   //  2 MB: [1024,1024]
  u16* qkv    = (u16*)(ws + 16 * MB);   // 24 MB: [4096,3072]
  u16* Qr     = (u16*)(ws + 40 * MB);   //  8 MB: [B,H,S,64] (pre-scaled 1/8)
  u16* Kr     = (u16*)(ws + 48 * MB);   //  8 MB
  u16* Vt     = (u16*)(ws + 56 * MB);   //  8 MB: [B,H,64,S]
  u16* ao     = (u16*)(ws + 64 * MB);   //  8 MB: [4096,1024]

  cvt_all<<<8192, 256, 0, stream>>>(x, Wqkv, Wo, xb, wqkvb, wob);
  gemm_bt<u16><<<dim3(32, 24), 256, 0, stream>>>(xb, wqkvb, qkv, 4096, 3072, 1024);
  rope_qk<<<8192, 256, 0, stream>>>(qkv, pos, Qr, Kr);
  v_transpose<<<dim3(8, 32), 256, 0, stream>>>(qkv, Vt);
  attn3<<<2048, 128, 0, stream>>>(Qr, Kr, Vt, ao);
  gemm_bt<float><<<dim3(32, 8), 256, 0, stream>>>(ao, wob, out, 4096, 1024, 1024);
}